// Round 1
// baseline (1212.911 us; speedup 1.0000x reference)
//
#include <hip/hip_runtime.h>
#include <hip/hip_bf16.h>
#include <cstdint>
#include <cstddef>

typedef __attribute__((ext_vector_type(8))) short short8;
typedef __attribute__((ext_vector_type(4))) float f32x4;

// Shapes: B=128, T-1=31, E=300, H=512, 3H=1536, V=32000, M_ALL=3968

// ---------------------------------------------------------------------------
// K1: hidden0 = relu(concat(g,t) @ W_feat + b_feat)   [128,256]@[256,512]
__global__ __launch_bounds__(512) void k_hidden0(
    const float* __restrict__ g_feat, const float* __restrict__ t_feat,
    const float* __restrict__ W_feat, const float* __restrict__ b_feat,
    float* __restrict__ h_cur) {
  __shared__ float inp[256];
  const int b = blockIdx.x;
  const int tid = threadIdx.x;  // 512
  if (tid < 128) inp[tid] = g_feat[b * 128 + tid];
  else if (tid < 256) inp[tid] = t_feat[b * 128 + tid - 128];
  __syncthreads();
  float acc = b_feat[tid];
#pragma unroll 8
  for (int k = 0; k < 256; ++k) acc = fmaf(inp[k], W_feat[k * 512 + tid], acc);
  h_cur[b * 512 + tid] = fmaxf(acc, 0.f);
}

// ---------------------------------------------------------------------------
// K2: gi_all[r=t*128+b][g] = x(t,b) @ W_ih^T + b_ih (+ b_hh for r,z gates)
// M=3968, N=1536, K=300. fp32 tiled SGEMM, BM=BN=64, BK=16, 4x4 micro.
__global__ __launch_bounds__(256) void k_gi(
    const float* __restrict__ lang, const float* __restrict__ W_ih,
    const float* __restrict__ b_ih, const float* __restrict__ b_hh,
    float* __restrict__ gi_all) {
  __shared__ float As[16][65];  // [k][m]
  __shared__ float Bs[16][65];  // [k][n]
  const int n0 = blockIdx.x * 64;
  const int m0 = blockIdx.y * 64;
  const int tid = threadIdx.x;
  const int tx = tid & 15, ty = tid >> 4;
  float acc[4][4] = {};
  for (int k0 = 0; k0 < 300; k0 += 16) {
    const int kk = tid & 15;
    const int r0 = tid >> 4;
    const int kg = k0 + kk;
    const bool kv = kg < 300;
#pragma unroll
    for (int i = 0; i < 4; ++i) {
      int row = r0 + i * 16;
      int r = m0 + row;
      int t = r >> 7, b = r & 127;
      As[kk][row] = kv ? lang[(size_t)b * 9600 + t * 300 + kg] : 0.f;
    }
#pragma unroll
    for (int i = 0; i < 4; ++i) {
      int n = r0 + i * 16;
      Bs[kk][n] = kv ? W_ih[(size_t)(n0 + n) * 300 + kg] : 0.f;
    }
    __syncthreads();
#pragma unroll
    for (int k = 0; k < 16; ++k) {
      float a[4], b[4];
#pragma unroll
      for (int i = 0; i < 4; ++i) a[i] = As[k][ty * 4 + i];
#pragma unroll
      for (int j = 0; j < 4; ++j) b[j] = Bs[k][tx * 4 + j];
#pragma unroll
      for (int i = 0; i < 4; ++i)
#pragma unroll
        for (int j = 0; j < 4; ++j) acc[i][j] = fmaf(a[i], b[j], acc[i][j]);
    }
    __syncthreads();
  }
#pragma unroll
  for (int i = 0; i < 4; ++i) {
    int r = m0 + ty * 4 + i;
#pragma unroll
    for (int j = 0; j < 4; ++j) {
      int c = n0 + tx * 4 + j;
      gi_all[(size_t)r * 1536 + c] =
          acc[i][j] + b_ih[c] + (c < 1024 ? b_hh[c] : 0.f);
    }
  }
}

// ---------------------------------------------------------------------------
// K3a: gh partials: gh[b][g] = h @ W_hh^T, split-K (4 chunks of 128).
// M=128, N=1536. BM=64, BN=32, BK=16; grid (48, 2, 4).
__global__ __launch_bounds__(256) void k_gh(
    const float* __restrict__ h_cur, const float* __restrict__ W_hh,
    float* __restrict__ gh_part) {
  __shared__ float As[16][65];  // [k][m 0..63]
  __shared__ float Bs[16][36];  // [k][n 0..31]
  const int n0 = blockIdx.x * 32;
  const int m0 = blockIdx.y * 64;
  const int kz = blockIdx.z;  // K chunk of 128
  const int tid = threadIdx.x;
  const int tx = tid & 7, ty = tid >> 3;  // tx->n (4 each), ty->m (2 each)
  float acc[2][4] = {};
  for (int kt = 0; kt < 8; ++kt) {
    const int kbase = kz * 128 + kt * 16;
    const int kk = tid & 15, r0 = tid >> 4;
#pragma unroll
    for (int i = 0; i < 4; ++i) {
      int row = r0 + i * 16;
      As[kk][row] = h_cur[(size_t)(m0 + row) * 512 + kbase + kk];
    }
#pragma unroll
    for (int i = 0; i < 2; ++i) {
      int n = r0 + i * 16;
      Bs[kk][n] = W_hh[(size_t)(n0 + n) * 512 + kbase + kk];
    }
    __syncthreads();
#pragma unroll
    for (int k = 0; k < 16; ++k) {
      float a0 = As[k][ty * 2], a1 = As[k][ty * 2 + 1];
      float b[4];
#pragma unroll
      for (int j = 0; j < 4; ++j) b[j] = Bs[k][tx * 4 + j];
#pragma unroll
      for (int j = 0; j < 4; ++j) {
        acc[0][j] = fmaf(a0, b[j], acc[0][j]);
        acc[1][j] = fmaf(a1, b[j], acc[1][j]);
      }
    }
    __syncthreads();
  }
  float* dst = gh_part + (size_t)kz * (128 * 1536);
#pragma unroll
  for (int i = 0; i < 2; ++i) {
    int m = m0 + ty * 2 + i;
#pragma unroll
    for (int j = 0; j < 4; ++j)
      dst[(size_t)m * 1536 + n0 + tx * 4 + j] = acc[i][j];
  }
}

// ---------------------------------------------------------------------------
// K3b: gates + h update + bf16 cast of h into h_all[t]
__global__ __launch_bounds__(512) void k_gates(
    const float* __restrict__ gi_all, const float* __restrict__ gh_part,
    const float* __restrict__ b_hh, float* __restrict__ h_cur,
    __hip_bfloat16* __restrict__ h_all, int t) {
  const int b = blockIdx.x;    // 128
  const int j = threadIdx.x;   // 512
  const float* gi = gi_all + (size_t)(t * 128 + b) * 1536;
  float ghr = 0.f, ghz = 0.f, ghn = 0.f;
#pragma unroll
  for (int s = 0; s < 4; ++s) {
    const float* p = gh_part + (size_t)s * (128 * 1536) + (size_t)b * 1536;
    ghr += p[j];
    ghz += p[j + 512];
    ghn += p[j + 1024];
  }
  ghn += b_hh[1024 + j];
  float r = 1.f / (1.f + __expf(-(gi[j] + ghr)));
  float z = 1.f / (1.f + __expf(-(gi[j + 512] + ghz)));
  float n = tanhf(gi[j + 1024] + r * ghn);
  float h_old = h_cur[b * 512 + j];
  float hn = (1.f - z) * n + z * h_old;
  h_cur[b * 512 + j] = hn;
  h_all[((size_t)t * 128 + b) * 512 + j] = __float2bfloat16(hn);
}

// ---------------------------------------------------------------------------
// K4: transpose-convert W_cls [512,32000] f32 -> WT [32000,512] bf16
__global__ __launch_bounds__(256) void k_tcls(const float* __restrict__ W,
                                              __hip_bfloat16* __restrict__ WT) {
  __shared__ float tile[32][33];
  const int v0 = blockIdx.x * 32, k0 = blockIdx.y * 32;
  const int tx = threadIdx.x & 31, ty = threadIdx.x >> 5;  // 32x8
#pragma unroll
  for (int i = 0; i < 32; i += 8)
    tile[ty + i][tx] = W[(size_t)(k0 + ty + i) * 32000 + v0 + tx];  // [k][v]
  __syncthreads();
#pragma unroll
  for (int i = 0; i < 32; i += 8)
    WT[(size_t)(v0 + ty + i) * 512 + k0 + tx] = __float2bfloat16(tile[tx][ty + i]);
}

// ---------------------------------------------------------------------------
// K5: classifier GEMM, bf16 MFMA 16x16x32.
// C[r=t*128+b][v] = h_all[r,:] . WT[v,:] + b_cls[v]; out[(b*31+t)*32000+v]
// Tile 128x128, 4 waves (2x2 quadrants of 64x64), BK=64, K=512.
__global__ __launch_bounds__(256, 2) void k_cls_gemm(
    const __hip_bfloat16* __restrict__ Abf,   // [3968,512]
    const __hip_bfloat16* __restrict__ BTbf,  // [32000,512]
    const float* __restrict__ b_cls, float* __restrict__ out) {
  __shared__ unsigned short Al[128][72];  // [m][k], +8 pad
  __shared__ unsigned short Bl[128][72];  // [n][k], +8 pad
  const int nblk = blockIdx.x;  // 0..249
  const int tblk = blockIdx.y;  // 0..30 == t
  const int tid = threadIdx.x;
  const int wave = tid >> 6, lane = tid & 63;
  const int quad = lane >> 4, l16 = lane & 15;
  const int mw = (wave >> 1) * 64, nw = (wave & 1) * 64;

  f32x4 acc[4][4] = {};

  const unsigned short* Ag =
      (const unsigned short*)Abf + (size_t)tblk * 128 * 512;
  const unsigned short* Bg =
      (const unsigned short*)BTbf + (size_t)nblk * 128 * 512;

  for (int k0 = 0; k0 < 512; k0 += 64) {
    __syncthreads();  // protect previous iteration's reads
#pragma unroll
    for (int i = 0; i < 4; ++i) {
      int c = tid + i * 256;
      int row = c >> 3, c8 = c & 7;
      *(uint4*)(&Al[row][c8 * 8]) =
          *(const uint4*)(Ag + (size_t)row * 512 + k0 + c8 * 8);
      *(uint4*)(&Bl[row][c8 * 8]) =
          *(const uint4*)(Bg + (size_t)row * 512 + k0 + c8 * 8);
    }
    __syncthreads();
#pragma unroll
    for (int kc = 0; kc < 2; ++kc) {
      short8 a[4], b[4];
#pragma unroll
      for (int mt = 0; mt < 4; ++mt)
        a[mt] = *(const short8*)(&Al[mw + mt * 16 + l16][kc * 32 + quad * 8]);
#pragma unroll
      for (int nt = 0; nt < 4; ++nt)
        b[nt] = *(const short8*)(&Bl[nw + nt * 16 + l16][kc * 32 + quad * 8]);
#pragma unroll
      for (int mt = 0; mt < 4; ++mt)
#pragma unroll
        for (int nt = 0; nt < 4; ++nt)
          acc[mt][nt] = __builtin_amdgcn_mfma_f32_16x16x32_bf16(
              a[mt], b[nt], acc[mt][nt], 0, 0, 0);
    }
  }
  // epilogue: D row = quad*4+i, col = l16 within each 16x16 tile
#pragma unroll
  for (int nt = 0; nt < 4; ++nt) {
    int v = nblk * 128 + nw + nt * 16 + l16;
    float bc = b_cls[v];
#pragma unroll
    for (int mt = 0; mt < 4; ++mt) {
#pragma unroll
      for (int i = 0; i < 4; ++i) {
        int m = mw + mt * 16 + quad * 4 + i;  // == b (tile is one t)
        out[((size_t)m * 31 + tblk) * 32000 + v] = acc[mt][nt][i] + bc;
      }
    }
  }
}

// ---------------------------------------------------------------------------
extern "C" void kernel_launch(void* const* d_in, const int* in_sizes, int n_in,
                              void* d_out, int out_size, void* d_ws,
                              size_t ws_size, hipStream_t stream) {
  (void)in_sizes; (void)n_in; (void)out_size; (void)ws_size;
  const float* g_feat = (const float*)d_in[0];
  const float* t_feat = (const float*)d_in[1];
  const float* lang   = (const float*)d_in[2];
  // d_in[3] = lang_len (unused; num_words is static)
  const float* W_feat = (const float*)d_in[4];
  const float* b_feat = (const float*)d_in[5];
  const float* W_ih   = (const float*)d_in[6];
  const float* W_hh   = (const float*)d_in[7];
  const float* b_ih   = (const float*)d_in[8];
  const float* b_hh   = (const float*)d_in[9];
  const float* W_cls  = (const float*)d_in[10];
  const float* b_cls  = (const float*)d_in[11];
  float* out = (float*)d_out;

  char* ws = (char*)d_ws;
  float* h_cur   = (float*)(ws);                       // 128*512*4      = 256 KB
  float* gh_part = (float*)(ws + 262144);              // 4*128*1536*4   = 3 MB
  float* gi_all  = (float*)(ws + 3407872);             // 3968*1536*4    = 24.4 MB
  __hip_bfloat16* h_all = (__hip_bfloat16*)(ws + 27787264);  // 3968*512*2 = 4 MB
  __hip_bfloat16* WT    = (__hip_bfloat16*)(ws + 31850496);  // 32000*512*2 = 32.8 MB
  // total ws use: ~64.7 MB

  k_hidden0<<<128, 512, 0, stream>>>(g_feat, t_feat, W_feat, b_feat, h_cur);
  k_gi<<<dim3(24, 62), 256, 0, stream>>>(lang, W_ih, b_ih, b_hh, gi_all);
  k_tcls<<<dim3(1000, 16), 256, 0, stream>>>(W_cls, WT);
  for (int t = 0; t < 31; ++t) {
    k_gh<<<dim3(48, 2, 4), 256, 0, stream>>>(h_cur, W_hh, gh_part);
    k_gates<<<128, 512, 0, stream>>>(gi_all, gh_part, b_hh, h_cur, h_all, t);
  }
  k_cls_gemm<<<dim3(250, 31), 256, 0, stream>>>(h_all, WT, b_cls, out);
}